// Round 3
// baseline (287.196 us; speedup 1.0000x reference)
//
#include <hip/hip_runtime.h>
#include <hip/hip_bf16.h>

typedef __bf16 bf16;
typedef __bf16 bf16x8 __attribute__((ext_vector_type(8)));
typedef float f32x4 __attribute__((ext_vector_type(4)));

#define HID 4096
#define QKVN 6144
#define NQH 32
#define NKVH 8
#define HD 128
#define MAXLEN 8192
#define PAST 4096
#define SQ 16
#define NC 33           // 32 chunks of 128 past keys + 1 chunk of 16 new keys
#define CHUNK 128
#define SCALE 0.08838834764831845f
#define NEGBIG (-30000.0f)

__device__ __forceinline__ f32x4 mfma16(bf16x8 a, bf16x8 b, f32x4 c) {
  return __builtin_amdgcn_mfma_f32_16x16x32_bf16(a, b, c, 0, 0, 0);
}

// Load 8 consecutive fp32 and round to bf16 fragment (16B-aligned source).
__device__ __forceinline__ bf16x8 load8f(const float* p) {
  const f32x4* q = (const f32x4*)p;
  f32x4 a = q[0], b = q[1];
  bf16x8 r;
  r[0] = (bf16)a[0]; r[1] = (bf16)a[1]; r[2] = (bf16)a[2]; r[3] = (bf16)a[3];
  r[4] = (bf16)b[0]; r[5] = (bf16)b[1]; r[6] = (bf16)b[2]; r[7] = (bf16)b[3];
  return r;
}

// ---------------- Kernel 1: QKV GEMM (16 x 4096) @ (6144 x 4096)^T -> fp32 ----------------
__global__ __launch_bounds__(256) void qkv_kernel(const float* __restrict__ x,
                                                  const float* __restrict__ wq,
                                                  float* __restrict__ qkv_acc) {
  int tid = threadIdx.x, lane = tid & 63, wv = tid >> 6;
  int l15 = lane & 15, quad = lane >> 4;
  int n = blockIdx.x * 16 + l15;
  const float* wrow = wq + (size_t)n * HID + quad * 8;
  const float* xrow = x + (size_t)l15 * HID + quad * 8;
  f32x4 acc = {0.f, 0.f, 0.f, 0.f};
  int kbeg = wv * (HID / 4);
#pragma unroll 8
  for (int k = 0; k < HID / 4; k += 32) {
    bf16x8 a = load8f(xrow + kbeg + k);
    bf16x8 b = load8f(wrow + kbeg + k);
    acc = mfma16(a, b, acc);
  }
  __shared__ __align__(16) float red[4][64][4];
  *(f32x4*)(&red[wv][lane][0]) = acc;
  __syncthreads();
  if (wv == 0) {
#pragma unroll
    for (int r = 0; r < 4; ++r) {
      float v = red[0][lane][r] + red[1][lane][r] + red[2][lane][r] + red[3][lane][r];
      qkv_acc[(quad * 4 + r) * QKVN + blockIdx.x * 16 + l15] = v;
    }
  }
}

// ---------------- Kernel 2: attention partials (flash-decoding style) ----------------
template <bool NEW>
__device__ void attn_body(int kvh, int c,
                          const float* __restrict__ ck, const float* __restrict__ cv,
                          const float* __restrict__ qkv_acc,
                          bf16* __restrict__ Opart, float* __restrict__ ml,
                          bf16* Vt, bf16* Pl) {
  int tid = threadIdx.x, lane = tid & 63, wv = tid >> 6;
  int l15 = lane & 15, quad = lane >> 4;
  int qh = kvh * 4 + wv;
  int cs = c * CHUNK;

  // ---- stage V transposed into LDS: Vt[d][key], row stride 136 ----
  if (!NEW) {
    int key = tid & 127;
    int dr = (tid >> 7) * 64;
    const float* vrow = cv + ((size_t)kvh * MAXLEN + cs + key) * HD + dr;
#pragma unroll
    for (int mb = 0; mb < 8; ++mb) {
      bf16x8 v = load8f(vrow + mb * 8);
#pragma unroll
      for (int i = 0; i < 8; ++i) Vt[(dr + mb * 8 + i) * 136 + key] = v[i];
    }
  } else {
    int key = tid & 15;
    int dr = (tid >> 4) * 8;
    const float* vsrc = qkv_acc + (size_t)key * QKVN + (PAST + NKVH * HD) + kvh * HD + dr;
#pragma unroll
    for (int i = 0; i < 8; ++i) {
      Vt[(dr + i) * 136 + key] = (bf16)vsrc[i];
      Vt[(dr + i) * 136 + 16 + key] = (bf16)0.f;  // zero pad keys 16..31
    }
  }
  __syncthreads();

  // ---- Q fragments: RoPE + scale, from fp32 qkv_acc ----
  bf16x8 afrag[4];
  {
    const float* qrow = qkv_acc + (size_t)l15 * QKVN + qh * HD;
    float fm = (float)l15;
#pragma unroll
    for (int kk = 0; kk < 4; ++kk) {
      bf16x8 a;
#pragma unroll
      for (int j = 0; j < 8; ++j) {
        int d = kk * 32 + quad * 8 + j;
        int dh = d & 63;
        float ang = fm * (float)dh * (1.0f / 64.0f);
        float sn, co;
        __sincosf(ang, &sn, &co);
        float qe = qrow[dh], qo = qrow[dh + 64];
        float v = (d < 64) ? (qe * co - qo * sn) : (qe * sn + qo * co);
        a[j] = (bf16)(v * SCALE);
      }
      afrag[kk] = a;
    }
  }

  // ---- scores S = Q K^T (D-layout: lane holds S[quad*4+r][nt*16+l15]) ----
  constexpr int NT = NEW ? 1 : 8;
  f32x4 sc[NT];
  if (!NEW) {
#pragma unroll
    for (int nt = 0; nt < NT; ++nt) {
      const float* krow = ck + ((size_t)kvh * MAXLEN + cs + nt * 16 + l15) * HD + quad * 8;
      f32x4 acc = {0.f, 0.f, 0.f, 0.f};
#pragma unroll
      for (int kk = 0; kk < 4; ++kk)
        acc = mfma16(afrag[kk], load8f(krow + kk * 32), acc);
      sc[nt] = acc;
    }
  } else {
    // new keys: RoPE'd K built from qkv_acc, position t = l15
    const float* krow = qkv_acc + (size_t)l15 * QKVN + PAST + kvh * HD;
    float ft = (float)l15;
    f32x4 acc = {0.f, 0.f, 0.f, 0.f};
#pragma unroll
    for (int kk = 0; kk < 4; ++kk) {
      bf16x8 b;
#pragma unroll
      for (int j = 0; j < 8; ++j) {
        int d = kk * 32 + quad * 8 + j;
        int dh = d & 63;
        float ang = ft * (float)dh * (1.0f / 64.0f);
        float sn, co;
        __sincosf(ang, &sn, &co);
        float ke = krow[dh], ko = krow[dh + 64];
        b[j] = (bf16)((d < 64) ? (ke * co - ko * sn) : (ke * sn + ko * co));
      }
      acc = mfma16(afrag[kk], b, acc);
    }
    // causal mask: key t = l15 allowed iff t <= m (m = quad*4+r)
#pragma unroll
    for (int r = 0; r < 4; ++r)
      if (l15 > quad * 4 + r) acc[r] = NEGBIG;
    sc[0] = acc;
  }

  // ---- per-chunk softmax (rows across the 16 lanes of each quad group) ----
  float mx[4], sm[4];
#pragma unroll
  for (int r = 0; r < 4; ++r) {
    float v = sc[0][r];
#pragma unroll
    for (int nt = 1; nt < NT; ++nt) v = fmaxf(v, sc[nt][r]);
    v = fmaxf(v, __shfl_xor(v, 1));
    v = fmaxf(v, __shfl_xor(v, 2));
    v = fmaxf(v, __shfl_xor(v, 4));
    v = fmaxf(v, __shfl_xor(v, 8));
    mx[r] = v;
  }
#pragma unroll
  for (int nt = 0; nt < NT; ++nt)
#pragma unroll
    for (int r = 0; r < 4; ++r) sc[nt][r] = __expf(sc[nt][r] - mx[r]);
#pragma unroll
  for (int r = 0; r < 4; ++r) {
    float v = 0.f;
#pragma unroll
    for (int nt = 0; nt < NT; ++nt) v += sc[nt][r];
    v += __shfl_xor(v, 1);
    v += __shfl_xor(v, 2);
    v += __shfl_xor(v, 4);
    v += __shfl_xor(v, 8);
    sm[r] = v;
  }

  // ---- P -> LDS (C-layout to A-layout transform), bf16 ----
  bf16* Pw = Pl + wv * 16 * 136;
#pragma unroll
  for (int nt = 0; nt < NT; ++nt)
#pragma unroll
    for (int r = 0; r < 4; ++r)
      Pw[(quad * 4 + r) * 136 + nt * 16 + l15] = (bf16)sc[nt][r];
  if (NEW) {
#pragma unroll
    for (int r = 0; r < 4; ++r)
      Pw[(quad * 4 + r) * 136 + 16 + l15] = (bf16)0.f;  // zero pad keys 16..31
  }
  // Cross-lane LDS RAW (C-layout write -> A-layout read): must barrier.
  __syncthreads();

  // ---- O = P V, store bf16 partial + fp32 (m, l) ----
  constexpr int KI = NEW ? 1 : 4;
  int prow = ((kvh * NC + c) * 4 + wv) * 16;
  bf16* ob = Opart + (size_t)prow * 128;
#pragma unroll
  for (int nt2 = 0; nt2 < 8; ++nt2) {
    f32x4 acc = {0.f, 0.f, 0.f, 0.f};
#pragma unroll
    for (int kk = 0; kk < KI; ++kk) {
      bf16x8 a = *(const bf16x8*)(Pw + l15 * 136 + kk * 32 + quad * 8);
      bf16x8 b = *(const bf16x8*)(Vt + (nt2 * 16 + l15) * 136 + kk * 32 + quad * 8);
      acc = mfma16(a, b, acc);
    }
#pragma unroll
    for (int r = 0; r < 4; ++r)
      ob[(quad * 4 + r) * 128 + nt2 * 16 + l15] = (bf16)acc[r];
  }
  if (l15 == 0) {
#pragma unroll
    for (int r = 0; r < 4; ++r) {
      ml[(size_t)(prow + quad * 4 + r) * 2] = mx[r];
      ml[(size_t)(prow + quad * 4 + r) * 2 + 1] = sm[r];
    }
  }
}

__global__ __launch_bounds__(256) void attn_kernel(const float* __restrict__ ck,
                                                   const float* __restrict__ cv,
                                                   const float* __restrict__ qkv_acc,
                                                   bf16* __restrict__ Opart,
                                                   float* __restrict__ ml) {
  __shared__ __align__(16) bf16 VtLds[128 * 136];
  __shared__ __align__(16) bf16 PLds[4 * 16 * 136];
  int c = blockIdx.x % NC;
  int kvh = blockIdx.x / NC;
  if (c == NC - 1)
    attn_body<true>(kvh, c, ck, cv, qkv_acc, Opart, ml, VtLds, PLds);
  else
    attn_body<false>(kvh, c, ck, cv, qkv_acc, Opart, ml, VtLds, PLds);
}

// ---------------- Kernel 3: combine partials across chunks ----------------
__global__ __launch_bounds__(256) void combine_kernel(const bf16* __restrict__ Opart,
                                                      const float* __restrict__ ml,
                                                      bf16* __restrict__ attn_out) {
  int tid = threadIdx.x, lane = tid & 63, wv = tid >> 6;
  int gw = blockIdx.x * 4 + wv;  // 0..511
  int qh = gw >> 4, srow = gw & 15;
  int kvh = qh >> 2, lw = qh & 3;
  int rowbase = ((kvh * NC) * 4 + lw) * 16 + srow;  // chunk-0 row; chunk stride = 64 rows
  const float* mlb = ml + (size_t)rowbase * 2;
  float m_c = NEGBIG, l_c = 0.f;
  if (lane < NC) {
    m_c = mlb[(size_t)lane * 128];       // 64 rows * 2 floats per chunk
    l_c = mlb[(size_t)lane * 128 + 1];
  }
  float M = m_c;
  M = fmaxf(M, __shfl_xor(M, 1));
  M = fmaxf(M, __shfl_xor(M, 2));
  M = fmaxf(M, __shfl_xor(M, 4));
  M = fmaxf(M, __shfl_xor(M, 8));
  M = fmaxf(M, __shfl_xor(M, 16));
  M = fmaxf(M, __shfl_xor(M, 32));
  float w = (lane < NC) ? __expf(m_c - M) : 0.f;
  float Lp = w * l_c;
  Lp += __shfl_xor(Lp, 1);
  Lp += __shfl_xor(Lp, 2);
  Lp += __shfl_xor(Lp, 4);
  Lp += __shfl_xor(Lp, 8);
  Lp += __shfl_xor(Lp, 16);
  Lp += __shfl_xor(Lp, 32);
  float a0 = 0.f, a1 = 0.f;
  const bf16* ob = Opart + (size_t)rowbase * 128;
  for (int cc = 0; cc < NC; ++cc) {
    float wc = __shfl(w, cc);
    const bf16* oc = ob + (size_t)cc * 64 * 128;
    a0 += wc * (float)oc[lane];
    a1 += wc * (float)oc[64 + lane];
  }
  float inv = 1.f / Lp;
  attn_out[srow * HID + qh * HD + lane] = (bf16)(a0 * inv);
  attn_out[srow * HID + qh * HD + 64 + lane] = (bf16)(a1 * inv);
}

// ---------------- Kernel 4: out projection (16 x 4096) @ (4096 x 4096)^T -> fp32 ----------------
__global__ __launch_bounds__(256) void proj_kernel(const bf16* __restrict__ attn_out,
                                                   const float* __restrict__ wo,
                                                   float* __restrict__ out) {
  int tid = threadIdx.x, lane = tid & 63, wv = tid >> 6;
  int l15 = lane & 15, quad = lane >> 4;
  int n = blockIdx.x * 16 + l15;
  const float* wrow = wo + (size_t)n * HID + quad * 8;
  const bf16* arow = attn_out + (size_t)l15 * HID + quad * 8;
  f32x4 acc = {0.f, 0.f, 0.f, 0.f};
  int kbeg = wv * (HID / 4);
#pragma unroll 8
  for (int k = 0; k < HID / 4; k += 32) {
    bf16x8 a = *(const bf16x8*)(arow + kbeg + k);
    bf16x8 b = load8f(wrow + kbeg + k);
    acc = mfma16(a, b, acc);
  }
  __shared__ __align__(16) float red[4][64][4];
  *(f32x4*)(&red[wv][lane][0]) = acc;
  __syncthreads();
  if (wv == 0) {
#pragma unroll
    for (int r = 0; r < 4; ++r) {
      float v = red[0][lane][r] + red[1][lane][r] + red[2][lane][r] + red[3][lane][r];
      out[(quad * 4 + r) * HID + blockIdx.x * 16 + l15] = v;
    }
  }
}

extern "C" void kernel_launch(void* const* d_in, const int* in_sizes, int n_in,
                              void* d_out, int out_size, void* d_ws, size_t ws_size,
                              hipStream_t stream) {
  const float* x       = (const float*)d_in[0];
  const float* w_qkv   = (const float*)d_in[1];
  const float* w_out   = (const float*)d_in[2];
  const float* cache_k = (const float*)d_in[3];
  const float* cache_v = (const float*)d_in[4];
  float* out = (float*)d_out;

  // ws layout:
  //   qkv_acc : 16*6144 fp32                 (384 KB)
  //   ml      : 8*33*4*16*2 fp32             (132 KB)
  //   attn_out: 16*4096 bf16                 (128 KB)
  //   Opart   : 8*33*4*16*128 bf16           (4.33 MB)
  float* qkv_acc = (float*)d_ws;
  float* ml = qkv_acc + SQ * QKVN;
  bf16* attn_out = (bf16*)(ml + (size_t)NKVH * NC * 4 * 16 * 2);
  bf16* Opart = attn_out + (size_t)SQ * HID;

  hipLaunchKernelGGL(qkv_kernel, dim3(QKVN / 16), dim3(256), 0, stream, x, w_qkv, qkv_acc);
  hipLaunchKernelGGL(attn_kernel, dim3(NKVH * NC), dim3(256), 0, stream, cache_k, cache_v, qkv_acc, Opart, ml);
  hipLaunchKernelGGL(combine_kernel, dim3(128), dim3(256), 0, stream, Opart, ml, attn_out);
  hipLaunchKernelGGL(proj_kernel, dim3(HID / 16), dim3(256), 0, stream, attn_out, w_out, out);
}

// Round 4
// 255.215 us; speedup vs baseline: 1.1253x; 1.1253x over previous
//
#include <hip/hip_runtime.h>
#include <hip/hip_bf16.h>

typedef __bf16 bf16;
typedef __bf16 bf16x4 __attribute__((ext_vector_type(4)));
typedef __bf16 bf16x8 __attribute__((ext_vector_type(8)));
typedef float f32x4 __attribute__((ext_vector_type(4)));

#define HID 4096
#define QKVN 6144
#define NQH 32
#define NKVH 8
#define HD 128
#define MAXLEN 8192
#define PAST 4096
#define SQ 16
#define SCALE 0.08838834764831845f
#define NEGBIG (-30000.0f)

// GEMM K-split config
#define KS 8          // K splits (blocks per N-tile)
#define KPB 512       // K elements per block
#define WSTR 520      // LDS row stride (elements) for W tile: 1040B, 16B-mult, bank-uniform
// attention chunking
#define ACH 64        // keys per past chunk
#define NCH 65        // 64 past chunks + 1 new chunk

__device__ __forceinline__ f32x4 mfma16(bf16x8 a, bf16x8 b, f32x4 c) {
  return __builtin_amdgcn_mfma_f32_16x16x32_bf16(a, b, c, 0, 0, 0);
}

__device__ __forceinline__ bf16x8 load8f(const float* p) {
  const f32x4* q = (const f32x4*)p;
  f32x4 a = q[0], b = q[1];
  bf16x8 r;
  r[0] = (bf16)a[0]; r[1] = (bf16)a[1]; r[2] = (bf16)a[2]; r[3] = (bf16)a[3];
  r[4] = (bf16)b[0]; r[5] = (bf16)b[1]; r[6] = (bf16)b[2]; r[7] = (bf16)b[3];
  return r;
}

// fragment-major index: element (k, m) of a 16-row operand, A- or B-layout alike.
// lane (l15, quad) reads 16B at octet (k>>3): addr = ((k>>3)*16 + m)*8 + (k&7)
__device__ __forceinline__ int fmidx(int k, int m) {
  return ((k >> 3) * 16 + m) * 8 + (k & 7);
}

// ---------------- Kernel 0: X -> fragment-major bf16 ----------------
__global__ __launch_bounds__(256) void xprep_kernel(const float* __restrict__ x,
                                                    bf16* __restrict__ xf) {
  int id = blockIdx.x * 256 + threadIdx.x;   // 8192 = 16 m * 512 octets
  int m = id & 15, o = id >> 4;
  bf16x8 v = load8f(x + (size_t)m * HID + o * 8);
  *(bf16x8*)(xf + (size_t)(o * 16 + m) * 8) = v;
}

// ---------------- GEMM: C16[m][n] partial = A[16][K] . W[n][K]^T over one K-slice ----------------
// afrag: fragment-major bf16 A (full K).  partial[((kq*NT + nt)*16 + m)*16 + nl]
template <int NT>
__global__ __launch_bounds__(256) void gemm16_kernel(const bf16* __restrict__ afrag,
                                                     const float* __restrict__ w,
                                                     float* __restrict__ partial) {
  int tid = threadIdx.x, lane = tid & 63, wv = tid >> 6;
  int l15 = lane & 15, quad = lane >> 4;
  int nt = blockIdx.x % NT, kq = blockIdx.x / NT;

  __shared__ __align__(16) bf16 Wt[16 * WSTR];
  __shared__ __align__(16) float red[4][64][4];

  // ---- stage W tile 16 x 512 fp32 -> bf16 LDS, fully coalesced ----
  const float* wb = w + (size_t)(nt * 16) * HID + kq * KPB;
  int r2 = tid >> 7;        // 0..1 (2 rows per iteration)
  int c4 = tid & 127;       // float4 column
  f32x4 stg[8];
#pragma unroll
  for (int it = 0; it < 8; ++it)
    stg[it] = *(const f32x4*)(wb + (size_t)(it * 2 + r2) * HID + c4 * 4);

  // ---- A fragments (coalesced 16B/lane, independent of LDS) ----
  int obase = kq * 64 + wv * 16;   // octet base for this wave (K = kq*512 + wv*128)
  bf16x8 af[4];
#pragma unroll
  for (int kk = 0; kk < 4; ++kk)
    af[kk] = *(const bf16x8*)(afrag + (size_t)((obase + kk * 4 + quad) * 16 + l15) * 8);

#pragma unroll
  for (int it = 0; it < 8; ++it) {
    bf16x4 t;
    t[0] = (bf16)stg[it][0]; t[1] = (bf16)stg[it][1];
    t[2] = (bf16)stg[it][2]; t[3] = (bf16)stg[it][3];
    *(bf16x4*)(Wt + (it * 2 + r2) * WSTR + c4 * 4) = t;
  }
  __syncthreads();

  // ---- MFMA over this wave's 128-K chunk ----
  f32x4 acc = {0.f, 0.f, 0.f, 0.f};
#pragma unroll
  for (int kk = 0; kk < 4; ++kk) {
    bf16x8 b = *(const bf16x8*)(Wt + l15 * WSTR + wv * 128 + kk * 32 + quad * 8);
    acc = mfma16(af[kk], b, acc);
  }

  // ---- reduce 4 waves, write 16x16 partial ----
  *(f32x4*)(&red[wv][lane][0]) = acc;
  __syncthreads();
  if (wv == 0) {
#pragma unroll
    for (int r = 0; r < 4; ++r) {
      float v = red[0][lane][r] + red[1][lane][r] + red[2][lane][r] + red[3][lane][r];
      partial[((size_t)(kq * NT + nt) * 16 + (quad * 4 + r)) * 16 + l15] = v;
    }
  }
}

// ---------------- qkv finish: 8-way reduce + RoPE -> Qfrag/Kfrag bf16, Vnew bf16 ----------------
__device__ __forceinline__ float sum_part(const float* p, int NT, int n, int m) {
  float s = 0.f;
#pragma unroll
  for (int q = 0; q < KS; ++q)
    s += p[((size_t)(q * NT + (n >> 4)) * 16 + m) * 16 + (n & 15)];
  return s;
}

__global__ __launch_bounds__(256) void qkv_finish_kernel(const float* __restrict__ pq,
                                                         bf16* __restrict__ Qf,
                                                         bf16* __restrict__ Kf,
                                                         bf16* __restrict__ Vn) {
  int id = blockIdx.x * 256 + threadIdx.x;   // 57344 total
  if (id < 32768) {           // Q: 32 heads x 16 m x 64 pairs
    int qh = id >> 10, m = (id >> 6) & 15, j = id & 63;
    float e = sum_part(pq, 384, qh * 128 + j, m);
    float o = sum_part(pq, 384, qh * 128 + 64 + j, m);
    float sn, co;
    __sincosf((float)m * (float)j * (1.0f / 64.0f), &sn, &co);
    Qf[qh * 2048 + fmidx(j, m)] = (bf16)((e * co - o * sn) * SCALE);
    Qf[qh * 2048 + fmidx(j + 64, m)] = (bf16)((e * sn + o * co) * SCALE);
  } else if (id < 40960) {    // K: 8 heads x 16 m x 64 pairs
    int v = id - 32768;
    int kvh = v >> 10, m = (v >> 6) & 15, j = v & 63;
    float e = sum_part(pq, 384, 4096 + kvh * 128 + j, m);
    float o = sum_part(pq, 384, 4096 + kvh * 128 + 64 + j, m);
    float sn, co;
    __sincosf((float)m * (float)j * (1.0f / 64.0f), &sn, &co);
    Kf[kvh * 2048 + fmidx(j, m)] = (bf16)(e * co - o * sn);
    Kf[kvh * 2048 + fmidx(j + 64, m)] = (bf16)(e * sn + o * co);
  } else if (id < 57344) {    // V: 8 heads x 16 m x 128 d
    int v = id - 40960;
    int kvh = v >> 11, m = (v >> 7) & 15, d = v & 127;
    Vn[kvh * 2048 + m * 128 + d] = (bf16)sum_part(pq, 384, 5120 + kvh * 128 + d, m);
  }
}

// ---------------- attention partials ----------------
template <bool NEW>
__device__ void attn_body(int kvh, int c,
                          const float* __restrict__ ck, const float* __restrict__ cv,
                          const bf16* __restrict__ Qf, const bf16* __restrict__ Kf,
                          const bf16* __restrict__ Vn,
                          bf16* __restrict__ Opart, float* __restrict__ ml,
                          bf16* Kt, bf16* Vt, bf16* Pl) {
  int tid = threadIdx.x, lane = tid & 63, wv = tid >> 6;
  int l15 = lane & 15, quad = lane >> 4;
  int qh = kvh * 4 + wv;
  int cs = c * ACH;

  // ---- staging ----
  if (!NEW) {
    // K tile 64 x 128 fp32, coalesced float4 -> Kt[key][d] stride 136
    {
      int kr = tid >> 5;           // +8 per iteration
      int kc4 = tid & 31;
      f32x4 kst[8];
#pragma unroll
      for (int it = 0; it < 8; ++it)
        kst[it] = *(const f32x4*)(ck + ((size_t)(kvh * MAXLEN + cs + it * 8 + kr)) * HD + kc4 * 4);
      // V tile 64 x 128 fp32 -> Vt[d][key] stride 72 (transposed; scatter-read, conflict-free write)
      int key = tid & 63, dg = tid >> 6;  // dg*32 .. +31
      f32x4 vst[8];
#pragma unroll
      for (int q4 = 0; q4 < 8; ++q4)
        vst[q4] = *(const f32x4*)(cv + ((size_t)(kvh * MAXLEN + cs + key)) * HD + dg * 32 + q4 * 4);
#pragma unroll
      for (int it = 0; it < 8; ++it) {
        bf16x4 t;
        t[0] = (bf16)kst[it][0]; t[1] = (bf16)kst[it][1];
        t[2] = (bf16)kst[it][2]; t[3] = (bf16)kst[it][3];
        *(bf16x4*)(Kt + (it * 8 + kr) * 136 + kc4 * 4) = t;
      }
#pragma unroll
      for (int q4 = 0; q4 < 8; ++q4)
#pragma unroll
        for (int i = 0; i < 4; ++i)
          Vt[(dg * 32 + q4 * 4 + i) * 72 + key] = (bf16)vst[q4][i];
    }
  } else {
    // V-new: 16 keys x 128 d bf16 -> Vt transposed, zero pad keys 16..31
    int key = tid >> 4, dg8 = tid & 15;
    bf16x8 v = *(const bf16x8*)(Vn + kvh * 2048 + key * 128 + dg8 * 8);
#pragma unroll
    for (int i = 0; i < 8; ++i) {
      Vt[(dg8 * 8 + i) * 72 + key] = v[i];
      Vt[(dg8 * 8 + i) * 72 + 16 + key] = (bf16)0.f;
    }
  }
  __syncthreads();

  // ---- Q fragments: coalesced 16B loads ----
  bf16x8 af[4];
#pragma unroll
  for (int kk = 0; kk < 4; ++kk)
    af[kk] = *(const bf16x8*)(Qf + qh * 2048 + ((kk * 4 + quad) * 16 + l15) * 8);

  // ---- scores ----
  constexpr int NT = NEW ? 1 : 4;
  f32x4 sc[NT];
  if (!NEW) {
#pragma unroll
    for (int nt = 0; nt < NT; ++nt) {
      f32x4 acc = {0.f, 0.f, 0.f, 0.f};
#pragma unroll
      for (int kk = 0; kk < 4; ++kk) {
        bf16x8 b = *(const bf16x8*)(Kt + (nt * 16 + l15) * 136 + kk * 32 + quad * 8);
        acc = mfma16(af[kk], b, acc);
      }
      sc[nt] = acc;
    }
  } else {
    f32x4 acc = {0.f, 0.f, 0.f, 0.f};
#pragma unroll
    for (int kk = 0; kk < 4; ++kk) {
      bf16x8 b = *(const bf16x8*)(Kf + kvh * 2048 + ((kk * 4 + quad) * 16 + l15) * 8);
      acc = mfma16(af[kk], b, acc);
    }
#pragma unroll
    for (int r = 0; r < 4; ++r)
      if (l15 > quad * 4 + r) acc[r] = NEGBIG;
    sc[0] = acc;
  }

  // ---- per-chunk softmax ----
  float mx[4], sm[4];
#pragma unroll
  for (int r = 0; r < 4; ++r) {
    float v = sc[0][r];
#pragma unroll
    for (int nt = 1; nt < NT; ++nt) v = fmaxf(v, sc[nt][r]);
    v = fmaxf(v, __shfl_xor(v, 1));
    v = fmaxf(v, __shfl_xor(v, 2));
    v = fmaxf(v, __shfl_xor(v, 4));
    v = fmaxf(v, __shfl_xor(v, 8));
    mx[r] = v;
  }
#pragma unroll
  for (int nt = 0; nt < NT; ++nt)
#pragma unroll
    for (int r = 0; r < 4; ++r) sc[nt][r] = __expf(sc[nt][r] - mx[r]);
#pragma unroll
  for (int r = 0; r < 4; ++r) {
    float v = 0.f;
#pragma unroll
    for (int nt = 0; nt < NT; ++nt) v += sc[nt][r];
    v += __shfl_xor(v, 1);
    v += __shfl_xor(v, 2);
    v += __shfl_xor(v, 4);
    v += __shfl_xor(v, 8);
    sm[r] = v;
  }

  // ---- P -> LDS (C- to A-layout), stride 72 ----
  bf16* Pw = Pl + wv * 16 * 72;
#pragma unroll
  for (int nt = 0; nt < NT; ++nt)
#pragma unroll
    for (int r = 0; r < 4; ++r)
      Pw[(quad * 4 + r) * 72 + nt * 16 + l15] = (bf16)sc[nt][r];
  if (NEW) {
#pragma unroll
    for (int r = 0; r < 4; ++r)
      Pw[(quad * 4 + r) * 72 + 16 + l15] = (bf16)0.f;
  }
  __syncthreads();   // cross-lane LDS RAW

  // ---- O = P V ----
  constexpr int KI = NEW ? 1 : 2;
  int rowblk = ((kvh * NCH + c) * 4 + wv) * 16;
  bf16* ob = Opart + (size_t)rowblk * 128;
#pragma unroll
  for (int nt2 = 0; nt2 < 8; ++nt2) {
    f32x4 acc = {0.f, 0.f, 0.f, 0.f};
#pragma unroll
    for (int kk = 0; kk < KI; ++kk) {
      bf16x8 a = *(const bf16x8*)(Pw + l15 * 72 + kk * 32 + quad * 8);
      bf16x8 b = *(const bf16x8*)(Vt + (nt2 * 16 + l15) * 72 + kk * 32 + quad * 8);
      acc = mfma16(a, b, acc);
    }
#pragma unroll
    for (int r = 0; r < 4; ++r)
      ob[(quad * 4 + r) * 128 + nt2 * 16 + l15] = (bf16)acc[r];
  }
  if (l15 == 0) {
#pragma unroll
    for (int r = 0; r < 4; ++r) {
      ml[(size_t)(rowblk + quad * 4 + r) * 2] = mx[r];
      ml[(size_t)(rowblk + quad * 4 + r) * 2 + 1] = sm[r];
    }
  }
}

__global__ __launch_bounds__(256) void attn_kernel(const float* __restrict__ ck,
                                                   const float* __restrict__ cv,
                                                   const bf16* __restrict__ Qf,
                                                   const bf16* __restrict__ Kf,
                                                   const bf16* __restrict__ Vn,
                                                   bf16* __restrict__ Opart,
                                                   float* __restrict__ ml) {
  __shared__ __align__(16) bf16 KtL[64 * 136];
  __shared__ __align__(16) bf16 VtL[128 * 72];
  __shared__ __align__(16) bf16 PL[4 * 16 * 72];
  int c = blockIdx.x % NCH;
  int kvh = blockIdx.x / NCH;
  if (c == NCH - 1)
    attn_body<true>(kvh, c, ck, cv, Qf, Kf, Vn, Opart, ml, KtL, VtL, PL);
  else
    attn_body<false>(kvh, c, ck, cv, Qf, Kf, Vn, Opart, ml, KtL, VtL, PL);
}

// ---------------- combine: merge 65 chunks -> attn_out fragment-major ----------------
__global__ __launch_bounds__(256) void combine_kernel(const bf16* __restrict__ Opart,
                                                      const float* __restrict__ ml,
                                                      bf16* __restrict__ attfm) {
  int tid = threadIdx.x, lane = tid & 63, wv = tid >> 6;
  int gw = blockIdx.x * 4 + wv;   // 0..511
  int qh = gw >> 4, srow = gw & 15;
  int kvh = qh >> 2, lw = qh & 3;
  int rowblk0 = ((kvh * NCH) * 4 + lw) * 16 + srow;   // chunk stride = 64 rows
  const float* mlb = ml + (size_t)rowblk0 * 2;
  float m1 = mlb[(size_t)lane * 128];
  float l1 = mlb[(size_t)lane * 128 + 1];
  float m2 = NEGBIG, l2 = 0.f;
  if (lane == 0) {
    m2 = mlb[(size_t)64 * 128];
    l2 = mlb[(size_t)64 * 128 + 1];
  }
  float M = fmaxf(m1, m2);
  M = fmaxf(M, __shfl_xor(M, 1));
  M = fmaxf(M, __shfl_xor(M, 2));
  M = fmaxf(M, __shfl_xor(M, 4));
  M = fmaxf(M, __shfl_xor(M, 8));
  M = fmaxf(M, __shfl_xor(M, 16));
  M = fmaxf(M, __shfl_xor(M, 32));
  float w1 = __expf(m1 - M);
  float w2 = (lane == 0) ? __expf(m2 - M) : 0.f;
  float Lp = w1 * l1 + w2 * l2;
  Lp += __shfl_xor(Lp, 1);
  Lp += __shfl_xor(Lp, 2);
  Lp += __shfl_xor(Lp, 4);
  Lp += __shfl_xor(Lp, 8);
  Lp += __shfl_xor(Lp, 16);
  Lp += __shfl_xor(Lp, 32);
  float a0 = 0.f, a1 = 0.f;
  const bf16* ob = Opart + (size_t)rowblk0 * 128;
  for (int cc = 0; cc < 64; ++cc) {
    float wc = __shfl(w1, cc);
    const bf16* oc = ob + (size_t)cc * 8192;
    a0 += wc * (float)oc[lane];
    a1 += wc * (float)oc[64 + lane];
  }
  {
    float wc = __shfl(w2, 0);
    const bf16* oc = ob + (size_t)64 * 8192;
    a0 += wc * (float)oc[lane];
    a1 += wc * (float)oc[64 + lane];
  }
  float inv = 1.f / Lp;
  int k1 = qh * 128 + lane, k2 = k1 + 64;
  attfm[fmidx(k1, srow)] = (bf16)(a0 * inv);
  attfm[fmidx(k2, srow)] = (bf16)(a1 * inv);
}

// ---------------- proj reduce: sum 8 partials -> fp32 out ----------------
__global__ __launch_bounds__(256) void proj_reduce_kernel(const float* __restrict__ pp,
                                                          float* __restrict__ out) {
  int flat = blockIdx.x * 256 + threadIdx.x;  // 16384 float4s
  int m = flat >> 10, n = (flat & 1023) * 4;
  f32x4 s = {0.f, 0.f, 0.f, 0.f};
#pragma unroll
  for (int q = 0; q < KS; ++q)
    s += *(const f32x4*)(pp + ((size_t)(q * 256 + (n >> 4)) * 16 + m) * 16 + (n & 15));
  *(f32x4*)(out + (size_t)m * HID + n) = s;
}

extern "C" void kernel_launch(void* const* d_in, const int* in_sizes, int n_in,
                              void* d_out, int out_size, void* d_ws, size_t ws_size,
                              hipStream_t stream) {
  const float* x       = (const float*)d_in[0];
  const float* w_qkv   = (const float*)d_in[1];
  const float* w_out   = (const float*)d_in[2];
  const float* cache_k = (const float*)d_in[3];
  const float* cache_v = (const float*)d_in[4];
  float* out = (float*)d_out;

  // ws layout (bytes, all 256B-aligned by construction)
  char* p = (char*)d_ws;
  bf16*  Xfrag = (bf16*)p;               p += (size_t)16 * HID * 2;            // 128 KB
  float* partQ = (float*)p;              p += (size_t)KS * 384 * 256 * 4;      // 3 MB
  bf16*  Qf    = (bf16*)p;               p += (size_t)NQH * 2048 * 2;          // 128 KB
  bf16*  Kf    = (bf16*)p;               p += (size_t)NKVH * 2048 * 2;         // 32 KB
  bf16*  Vn    = (bf16*)p;               p += (size_t)NKVH * 2048 * 2;         // 32 KB
  bf16*  Opart = (bf16*)p;               p += (size_t)NKVH * NCH * 4 * 16 * 128 * 2;  // 8.5 MB
  float* ml    = (float*)p;              p += (size_t)NKVH * NCH * 4 * 16 * 2 * 4;    // 266 KB
  bf16*  attfm = (bf16*)p;               p += (size_t)16 * HID * 2;            // 128 KB
  float* partP = (float*)p;              p += (size_t)KS * 256 * 256 * 4;      // 2 MB

  hipLaunchKernelGGL(xprep_kernel, dim3(32), dim3(256), 0, stream, x, Xfrag);
  hipLaunchKernelGGL((gemm16_kernel<384>), dim3(384 * KS), dim3(256), 0, stream, Xfrag, w_qkv, partQ);
  hipLaunchKernelGGL(qkv_finish_kernel, dim3(224), dim3(256), 0, stream, partQ, Qf, Kf, Vn);
  hipLaunchKernelGGL(attn_kernel, dim3(NKVH * NCH), dim3(256), 0, stream,
                     cache_k, cache_v, Qf, Kf, Vn, Opart, ml);
  hipLaunchKernelGGL(combine_kernel, dim3(128), dim3(256), 0, stream, Opart, ml, attfm);
  hipLaunchKernelGGL((gemm16_kernel<256>), dim3(256 * KS), dim3(256), 0, stream, attfm, w_out, partP);
  hipLaunchKernelGGL(proj_reduce_kernel, dim3(64), dim3(256), 0, stream, partP, out);
}